// Round 7
// baseline (1060.695 us; speedup 1.0000x reference)
//
#include <hip/hip_runtime.h>
#include <hip/hip_fp16.h>

#define N_NODES 100000
#define N_EDGES 1250000
#define DIM 64
#define EDGE_DIM 10
#define BN_EPS 1e-5f

#define BIN_NODES 160
#define NBINS 625            // 625 * 160 = 100000 exactly

// workspace layout (int units)
#define BDEG_OFF  0
#define SUMS_OFF  (BDEG_OFF + NBINS)          // 256 floats (BN)
#define BOFFS_OFF (SUMS_OFF + 256)            // NBINS+1
#define BCUR_OFF  (BOFFS_OFF + NBINS + 1)
#define RECS_OFF  (BCUR_OFF + NBINS)          // 6 ints / edge = 30 MB
#define XH_OFF    (RECS_OFF + 6 * N_EDGES)    // 6.4M halves = 3.2M ints
// total ≈ 10.70M ints ≈ 42.8 MB (R5 proved ws_size ≥ 43.1 MB)

__device__ __forceinline__ unsigned f2bf(float f) {
    unsigned b = __float_as_uint(f);
    return (b + 0x7FFFu + ((b >> 16) & 1u)) >> 16;   // RTNE
}

// -----------------------------------------------------------------------------
// prep: x -> fp16 copy + 625-bin dst histogram (LDS-privatized)
// -----------------------------------------------------------------------------
extern "C" __global__ __launch_bounds__(256)
void prep_kernel(const float* __restrict__ x, __half2* __restrict__ xh2,
                 const int* __restrict__ ei, int* __restrict__ bdeg)
{
    __shared__ int lhist[NBINS];
    int tid = threadIdx.x;
    for (int i = tid; i < NBINS; i += 256) lhist[i] = 0;
    __syncthreads();

    int t = blockIdx.x * 256 + tid;
    int stride = gridDim.x * 256;
    for (int i = t; i < N_NODES * DIM / 2; i += stride) {
        float2 v = ((const float2*)x)[i];
        xh2[i] = __floats2half2_rn(v.x, v.y);
    }
    for (int e = t; e < N_EDGES; e += stride) {
        unsigned d = (unsigned)ei[N_EDGES + e];
        d = d < N_NODES ? d : (N_NODES - 1);
        atomicAdd(&lhist[d / BIN_NODES], 1);
    }
    __syncthreads();
    for (int i = tid; i < NBINS; i += 256)
        if (lhist[i]) atomicAdd(&bdeg[i], lhist[i]);
}

// -----------------------------------------------------------------------------
// scan: exclusive prefix over 625 bins, one 1024-thread block
// -----------------------------------------------------------------------------
extern "C" __global__ __launch_bounds__(1024)
void scan_kernel(const int* __restrict__ bdeg, int* __restrict__ boffs,
                 int* __restrict__ bcur)
{
    __shared__ int s[1024];
    int tid = threadIdx.x;
    int v = (tid < NBINS) ? bdeg[tid] : 0;
    s[tid] = v;
    __syncthreads();
    #pragma unroll
    for (int off = 1; off < 1024; off <<= 1) {
        int t = (tid >= off) ? s[tid - off] : 0;
        __syncthreads();
        s[tid] += t;
        __syncthreads();
    }
    if (tid < NBINS) {
        int excl = s[tid] - v;
        boffs[tid] = excl;
        bcur[tid] = excl;
    }
    if (tid == 0) boffs[NBINS] = N_EDGES;
}

// -----------------------------------------------------------------------------
// scatter: record {src | dst_local<<17, 5x packed bf16 ea} -> bucket stream
// -----------------------------------------------------------------------------
extern "C" __global__ __launch_bounds__(256)
void scatter_kernel(const int* __restrict__ ei, const float* __restrict__ ea,
                    int* __restrict__ bcur, int* __restrict__ recs)
{
    int e = blockIdx.x * 256 + threadIdx.x;
    if (e >= N_EDGES) return;
    unsigned d = (unsigned)ei[N_EDGES + e];
    unsigned s = (unsigned)ei[e];
    d = d < N_NODES ? d : (N_NODES - 1);
    s = s < N_NODES ? s : (N_NODES - 1);
    unsigned bin = d / BIN_NODES;
    unsigned dl  = d - bin * BIN_NODES;         // < 160
    int pos = atomicAdd(&bcur[bin], 1);
    int* r = recs + (size_t)pos * 6;
    int2 w0, w1, w2;
    w0.x = (int)(s | (dl << 17));               // src<2^17, dl<2^8
    unsigned p0 = f2bf(ea[(size_t)e * EDGE_DIM + 0]) | (f2bf(ea[(size_t)e * EDGE_DIM + 1]) << 16);
    unsigned p1 = f2bf(ea[(size_t)e * EDGE_DIM + 2]) | (f2bf(ea[(size_t)e * EDGE_DIM + 3]) << 16);
    unsigned p2 = f2bf(ea[(size_t)e * EDGE_DIM + 4]) | (f2bf(ea[(size_t)e * EDGE_DIM + 5]) << 16);
    unsigned p3 = f2bf(ea[(size_t)e * EDGE_DIM + 6]) | (f2bf(ea[(size_t)e * EDGE_DIM + 7]) << 16);
    unsigned p4 = f2bf(ea[(size_t)e * EDGE_DIM + 8]) | (f2bf(ea[(size_t)e * EDGE_DIM + 9]) << 16);
    w0.y = (int)p0; w1.x = (int)p1; w1.y = (int)p2; w2.x = (int)p3; w2.y = (int)p4;
    ((int2*)r)[0] = w0;   // rec is 24 B -> 8 B aligned
    ((int2*)r)[1] = w1;
    ((int2*)r)[2] = w2;
}

// -----------------------------------------------------------------------------
// fused bucket kernel: one block per 160-node bucket.
//   phase 1: stream records, gather fp16 x[src], ds_add into sA[feat][161]
//   phase 2: += fp32 x (self), GEMM1 (W1,ReLU) -> T^T in sA, GEMM2 (W2,ReLU)
//            -> out + BN partial sums. 512 threads (8 waves).
// -----------------------------------------------------------------------------
extern "C" __global__ __launch_bounds__(512)
void gine_bucket_kernel(const __half* __restrict__ xh,
                        const float* __restrict__ x,
                        const int* __restrict__ boffs,
                        const int* __restrict__ recs,
                        const float* __restrict__ We,
                        const float* __restrict__ be,
                        const float* __restrict__ W1,
                        const float* __restrict__ b1,
                        const float* __restrict__ W2,
                        const float* __restrict__ b2,
                        float* __restrict__ out,
                        float* __restrict__ sums)
{
    __shared__ __align__(16) float sA[DIM * 161];   // [feat][node], 41.2 KB
    __shared__ __align__(16) float sW[DIM * DIM];   // W1 then W2, 16 KB

    int tid  = threadIdx.x;
    int lane = tid & 63;
    int wv   = tid >> 6;                 // 0..7
    int b    = blockIdx.x;
    int base = b * BIN_NODES;

    for (int i = tid; i < DIM * 161; i += 512) sA[i] = 0.0f;

    float wcol[EDGE_DIM];
    #pragma unroll
    for (int k = 0; k < EDGE_DIM; ++k) wcol[k] = We[k * DIM + lane];
    float bias = be[lane];
    __syncthreads();

    int stt = boffs[b];
    int end = boffs[b + 1];

    // ---- phase 1: edge aggregation, 4-edge groups per wave ----
    #pragma unroll 1
    for (int i = stt + wv * 4; i < end; i += 32) {
        int r0[4];
        unsigned ew[4][5];
        #pragma unroll
        for (int u = 0; u < 4; ++u) {
            int p = i + u;
            p = p < end ? p : end - 1;
            const int* r = recs + (size_t)p * 6;
            r0[u] = __builtin_amdgcn_readfirstlane(r[0]);
            #pragma unroll
            for (int k = 0; k < 5; ++k)
                ew[u][k] = (unsigned)__builtin_amdgcn_readfirstlane(r[1 + k]);
        }
        float xv[4];
        #pragma unroll
        for (int u = 0; u < 4; ++u) {
            int src = r0[u] & 0x1FFFF;
            xv[u] = __half2float(xh[(size_t)src * DIM + lane]);
        }
        #pragma unroll
        for (int u = 0; u < 4; ++u) {
            if (i + u < end) {
                float m = bias;
                #pragma unroll
                for (int k = 0; k < 5; ++k) {
                    unsigned w = ew[u][k];
                    m = fmaf(__uint_as_float(w << 16),         wcol[2 * k],     m);
                    m = fmaf(__uint_as_float(w & 0xFFFF0000u), wcol[2 * k + 1], m);
                }
                m = fmaxf(m + xv[u], 0.0f);
                int nl = (r0[u] >> 17) & 0xFF;
                atomicAdd(&sA[lane * 161 + nl], m);   // ds_add_f32, conflict-free
            }
        }
    }

    // load W1 while aggregation finishes
    for (int i = tid; i < DIM * DIM; i += 512) sW[i] = W1[i];
    __syncthreads();

    // ---- add fp32 self term: sA[f][nl] += x[base+nl][f] ----
    for (int idx = tid; idx < BIN_NODES * DIM; idx += 512) {
        int nl = idx >> 6;
        int f  = idx & 63;
        sA[f * 161 + nl] += x[(size_t)(base + nl) * DIM + f];
    }
    __syncthreads();

    // ---- phase 2: thread tile = 5 nodes x 4 feats (512 x 20 = 10240) ----
    int i0 = (tid & 31) * 5;    // node offset: 32 groups * 5 = 160
    int j0 = (tid >> 5) * 4;    // feat offset: 16 groups * 4 = 64

    float acc1[5][4] = {};
    #pragma unroll 4
    for (int k = 0; k < DIM; ++k) {
        float a0 = sA[k * 161 + i0 + 0];
        float a1 = sA[k * 161 + i0 + 1];
        float a2 = sA[k * 161 + i0 + 2];
        float a3 = sA[k * 161 + i0 + 3];
        float a4 = sA[k * 161 + i0 + 4];
        float4 bw = *(const float4*)&sW[k * DIM + j0];
        float bb[4] = {bw.x, bw.y, bw.z, bw.w};
        float aa[5] = {a0, a1, a2, a3, a4};
        #pragma unroll
        for (int a = 0; a < 5; ++a)
            #pragma unroll
            for (int c = 0; c < 4; ++c)
                acc1[a][c] = fmaf(aa[a], bb[c], acc1[a][c]);
    }
    __syncthreads();   // all GEMM1 reads of sA done

    float4 b1v = *(const float4*)&b1[j0];
    float b1a[4] = {b1v.x, b1v.y, b1v.z, b1v.w};
    // T^T back into sA: sA[(j0+c)*161 + i0+a]
    #pragma unroll
    for (int c = 0; c < 4; ++c) {
        #pragma unroll
        for (int a = 0; a < 5; ++a)
            sA[(j0 + c) * 161 + i0 + a] = fmaxf(acc1[a][c] + b1a[c], 0.0f);
    }
    // swap W1 -> W2
    __syncthreads();
    for (int i = tid; i < DIM * DIM; i += 512) sW[i] = W2[i];
    __syncthreads();

    float acc2[5][4] = {};
    #pragma unroll 4
    for (int k = 0; k < DIM; ++k) {
        float a0 = sA[k * 161 + i0 + 0];
        float a1 = sA[k * 161 + i0 + 1];
        float a2 = sA[k * 161 + i0 + 2];
        float a3 = sA[k * 161 + i0 + 3];
        float a4 = sA[k * 161 + i0 + 4];
        float4 bw = *(const float4*)&sW[k * DIM + j0];
        float bb[4] = {bw.x, bw.y, bw.z, bw.w};
        float aa[5] = {a0, a1, a2, a3, a4};
        #pragma unroll
        for (int a = 0; a < 5; ++a)
            #pragma unroll
            for (int c = 0; c < 4; ++c)
                acc2[a][c] = fmaf(aa[a], bb[c], acc2[a][c]);
    }

    float4 b2v = *(const float4*)&b2[j0];
    float b2a[4] = {b2v.x, b2v.y, b2v.z, b2v.w};
    float ps[4] = {0.f, 0.f, 0.f, 0.f};
    float pq[4] = {0.f, 0.f, 0.f, 0.f};
    #pragma unroll
    for (int a = 0; a < 5; ++a) {
        int n = base + i0 + a;     // always < N_NODES (625*160 = 100000)
        float4 w;
        w.x = fmaxf(acc2[a][0] + b2a[0], 0.0f);
        w.y = fmaxf(acc2[a][1] + b2a[1], 0.0f);
        w.z = fmaxf(acc2[a][2] + b2a[2], 0.0f);
        w.w = fmaxf(acc2[a][3] + b2a[3], 0.0f);
        *(float4*)&out[(size_t)n * DIM + j0] = w;
        ps[0] += w.x; ps[1] += w.y; ps[2] += w.z; ps[3] += w.w;
        pq[0] += w.x * w.x; pq[1] += w.y * w.y; pq[2] += w.z * w.z; pq[3] += w.w * w.w;
    }

    // reduce over the 32 lanes sharing j0 (lanes 0..31 / 32..63 of each wave)
    #pragma unroll
    for (int m = 1; m < 32; m <<= 1) {
        #pragma unroll
        for (int c = 0; c < 4; ++c) {
            ps[c] += __shfl_xor(ps[c], m, 64);
            pq[c] += __shfl_xor(pq[c], m, 64);
        }
    }
    if ((tid & 31) == 0) {
        #pragma unroll
        for (int c = 0; c < 4; ++c) {
            unsafeAtomicAdd(&sums[j0 + c], ps[c]);
            unsafeAtomicAdd(&sums[64 + j0 + c], pq[c]);
        }
    }
}

// -----------------------------------------------------------------------------
// BN stats + apply
// -----------------------------------------------------------------------------
extern "C" __global__ void bn_stats_kernel(float* __restrict__ sums,
                                           const float* __restrict__ gamma,
                                           const float* __restrict__ beta)
{
    int f = threadIdx.x;
    float inv_n = 1.0f / (float)N_NODES;
    float mean = sums[f] * inv_n;
    float var  = sums[64 + f] * inv_n - mean * mean;
    float sc   = gamma[f] * rsqrtf(var + BN_EPS);
    sums[128 + f] = sc;
    sums[192 + f] = beta[f] - mean * sc;
}

extern "C" __global__ __launch_bounds__(256)
void bn_apply_kernel(float* __restrict__ out, const float* __restrict__ sums)
{
    int j = blockIdx.x * 256 + threadIdx.x;
    int f0 = (j & 15) * 4;
    float4 sc = *(const float4*)&sums[128 + f0];
    float4 sh = *(const float4*)&sums[192 + f0];
    float4 v = ((float4*)out)[j];
    v.x = fmaf(v.x, sc.x, sh.x);
    v.y = fmaf(v.y, sc.y, sh.y);
    v.z = fmaf(v.z, sc.z, sh.z);
    v.w = fmaf(v.w, sc.w, sh.w);
    ((float4*)out)[j] = v;
}

extern "C" void kernel_launch(void* const* d_in, const int* in_sizes, int n_in,
                              void* d_out, int out_size, void* d_ws, size_t ws_size,
                              hipStream_t stream)
{
    const float* x     = (const float*)d_in[0];
    const int*   ei    = (const int*)  d_in[1];
    const float* ea    = (const float*)d_in[2];
    const float* We    = (const float*)d_in[3];
    const float* be    = (const float*)d_in[4];
    const float* W1    = (const float*)d_in[5];
    const float* b1    = (const float*)d_in[6];
    const float* W2    = (const float*)d_in[7];
    const float* b2    = (const float*)d_in[8];
    const float* gamma = (const float*)d_in[9];
    const float* beta  = (const float*)d_in[10];

    float* out  = (float*)d_out;
    int*   wsi  = (int*)d_ws;
    int*   bdeg = wsi + BDEG_OFF;
    float* sums = (float*)(wsi + SUMS_OFF);
    int*   boffs= wsi + BOFFS_OFF;
    int*   bcur = wsi + BCUR_OFF;
    int*   recs = wsi + RECS_OFF;
    __half* xh  = (__half*)(wsi + XH_OFF);

    // zero bdeg + BN sums (adjacent) in one memset
    hipMemsetAsync(wsi, 0, (size_t)(NBINS + 256) * sizeof(int), stream);

    prep_kernel<<<256, 256, 0, stream>>>(x, (__half2*)xh, ei, bdeg);
    scan_kernel<<<1, 1024, 0, stream>>>(bdeg, boffs, bcur);
    scatter_kernel<<<(N_EDGES + 255) / 256, 256, 0, stream>>>(ei, ea, bcur, recs);

    gine_bucket_kernel<<<NBINS, 512, 0, stream>>>(
        xh, x, boffs, recs, We, be, W1, b1, W2, b2, out, sums);

    bn_stats_kernel<<<1, 64, 0, stream>>>(sums, gamma, beta);

    bn_apply_kernel<<<(N_NODES * DIM / 4) / 256, 256, 0, stream>>>(out, sums);
}

// Round 8
// 809.423 us; speedup vs baseline: 1.3104x; 1.3104x over previous
//
#include <hip/hip_runtime.h>
#include <hip/hip_fp16.h>

#define N_NODES 100000
#define N_EDGES 1250000
#define DIM 64
#define EDGE_DIM 10
#define BN_EPS 1e-5f

#define BIN_NODES 64
#define NBINS 1563           // ceil(100000/64)
#define NSLICE 8
#define NCOUNT (NBINS * NSLICE)   // 12504

// workspace (int units)
#define HIST_OFF 0
#define SUMS_OFF (HIST_OFF + NCOUNT)          // 256 floats
#define CUR_OFF  (SUMS_OFF + 256)
#define OFFS_OFF (CUR_OFF + NCOUNT)           // NCOUNT+1
#define RECS_OFF 37770                        // 8-byte aligned; 6 ints/edge
#define XH_OFF   (RECS_OFF + 6 * N_EDGES)     // 6.4M halves
// total = 10,737,770 ints ≈ 42.95 MB (R5 proved ws_size ≥ 44 MB)

__device__ __forceinline__ unsigned f2bf(float f) {
    unsigned b = __float_as_uint(f);
    return (b + 0x7FFFu + ((b >> 16) & 1u)) >> 16;   // RTNE
}
__device__ __forceinline__ float bflo(unsigned w) { return __uint_as_float(w << 16); }
__device__ __forceinline__ float bfhi(unsigned w) { return __uint_as_float(w & 0xFFFF0000u); }

// -----------------------------------------------------------------------------
// prep: x -> fp16 copy + (bin,slice) histogram. slice = (e>>8)&7.
// -----------------------------------------------------------------------------
extern "C" __global__ __launch_bounds__(256)
void prep_kernel(const float* __restrict__ x, __half2* __restrict__ xh2,
                 const int* __restrict__ ei, int* __restrict__ hist)
{
    int t = blockIdx.x * 256 + threadIdx.x;
    int stride = gridDim.x * 256;
    for (int i = t; i < N_NODES * DIM / 2; i += stride) {
        float2 v = ((const float2*)x)[i];
        xh2[i] = __floats2half2_rn(v.x, v.y);
    }
    for (int e = t; e < N_EDGES; e += stride) {
        unsigned d = (unsigned)ei[N_EDGES + e];
        d = d < N_NODES ? d : (N_NODES - 1);
        int slice = (e >> 8) & 7;
        atomicAdd(&hist[(d >> 6) * NSLICE + slice], 1);
    }
}

// -----------------------------------------------------------------------------
// scan: exclusive prefix over 12504 counters, one 1024-thread block, 13 chunks
// -----------------------------------------------------------------------------
extern "C" __global__ __launch_bounds__(1024)
void scan_kernel(const int* __restrict__ hist, int* __restrict__ offs,
                 int* __restrict__ cur)
{
    __shared__ int s[1024];
    __shared__ int carry;
    int tid = threadIdx.x;
    if (tid == 0) carry = 0;
    __syncthreads();
    for (int c = 0; c < (NCOUNT + 1023) / 1024; ++c) {
        int idx = c * 1024 + tid;
        int v = (idx < NCOUNT) ? hist[idx] : 0;
        s[tid] = v;
        __syncthreads();
        #pragma unroll
        for (int off = 1; off < 1024; off <<= 1) {
            int tmp = (tid >= off) ? s[tid - off] : 0;
            __syncthreads();
            s[tid] += tmp;
            __syncthreads();
        }
        int excl = carry + s[tid] - v;
        if (idx < NCOUNT) { offs[idx] = excl; cur[idx] = excl; }
        __syncthreads();
        if (tid == 0) carry += s[1023];
        __syncthreads();
    }
    if (tid == 0) offs[NCOUNT] = N_EDGES;
}

// -----------------------------------------------------------------------------
// scatter: record {src | dst_local<<17, 5x packed bf16 ea} into (bin,slice)
// stream. ~100 hits per cursor; partial lines stay L2-resident.
// -----------------------------------------------------------------------------
extern "C" __global__ __launch_bounds__(256)
void scatter_kernel(const int* __restrict__ ei, const float* __restrict__ ea,
                    int* __restrict__ cur, int* __restrict__ recs)
{
    int e = blockIdx.x * 256 + threadIdx.x;
    if (e >= N_EDGES) return;
    unsigned d = (unsigned)ei[N_EDGES + e];
    unsigned s = (unsigned)ei[e];
    d = d < N_NODES ? d : (N_NODES - 1);
    s = s < N_NODES ? s : (N_NODES - 1);
    unsigned bin = d >> 6;
    unsigned dl  = d & 63;
    int slice = blockIdx.x & 7;    // == (e>>8)&7
    int pos = atomicAdd(&cur[bin * NSLICE + slice], 1);
    int* r = recs + (size_t)pos * 6;
    int2 w0, w1, w2;
    w0.x = (int)(s | (dl << 17));
    w0.y = (int)(f2bf(ea[(size_t)e * EDGE_DIM + 0]) | (f2bf(ea[(size_t)e * EDGE_DIM + 1]) << 16));
    w1.x = (int)(f2bf(ea[(size_t)e * EDGE_DIM + 2]) | (f2bf(ea[(size_t)e * EDGE_DIM + 3]) << 16));
    w1.y = (int)(f2bf(ea[(size_t)e * EDGE_DIM + 4]) | (f2bf(ea[(size_t)e * EDGE_DIM + 5]) << 16));
    w2.x = (int)(f2bf(ea[(size_t)e * EDGE_DIM + 6]) | (f2bf(ea[(size_t)e * EDGE_DIM + 7]) << 16));
    w2.y = (int)(f2bf(ea[(size_t)e * EDGE_DIM + 8]) | (f2bf(ea[(size_t)e * EDGE_DIM + 9]) << 16));
    ((int2*)r)[0] = w0;
    ((int2*)r)[1] = w1;
    ((int2*)r)[2] = w2;
}

// -----------------------------------------------------------------------------
// fused kernel: one block per 64-node bucket, 512 threads (8 waves).
// sA[feat][65]: init = x (fp32 self), edge phase ds_add (conflict-free),
// then GEMM1(ReLU) -> T^T in sA -> GEMM2(ReLU) -> out + BN partials.
// Edge phase: lane-parallel record loads + v_readlane broadcast (no mem chain).
// -----------------------------------------------------------------------------
extern "C" __global__ __launch_bounds__(512)
void gine_fused_kernel(const __half* __restrict__ xh,
                       const float* __restrict__ x,
                       const int* __restrict__ offs,
                       const int* __restrict__ recs,
                       const float* __restrict__ We,
                       const float* __restrict__ be,
                       const float* __restrict__ W1,
                       const float* __restrict__ b1,
                       const float* __restrict__ W2,
                       const float* __restrict__ b2,
                       float* __restrict__ out,
                       float* __restrict__ sums)
{
    __shared__ __align__(16) float sA[DIM * 65];   // [feat][node], 16.6 KB
    __shared__ __align__(16) float sW[DIM * DIM];  // W1 then W2, 16 KB

    int tid  = threadIdx.x;
    int lane = tid & 63;
    int wv   = tid >> 6;
    int b    = blockIdx.x;
    int base = b * BIN_NODES;

    // init sA with fp32 self term (transposed store), load W1
    #pragma unroll
    for (int it = 0; it < 2; ++it) {
        int f4   = it * 512 + tid;     // float4 index in 64x64 tile
        int node = f4 >> 4;
        int f0   = (f4 & 15) * 4;
        float4 v = make_float4(0.f, 0.f, 0.f, 0.f);
        if (base + node < N_NODES)
            v = *(const float4*)&x[(size_t)(base + node) * DIM + f0];
        sA[(f0 + 0) * 65 + node] = v.x;
        sA[(f0 + 1) * 65 + node] = v.y;
        sA[(f0 + 2) * 65 + node] = v.z;
        sA[(f0 + 3) * 65 + node] = v.w;
    }
    for (int i = tid; i < DIM * DIM; i += 512) sW[i] = W1[i];

    float wcol[EDGE_DIM];
    #pragma unroll
    for (int k = 0; k < EDGE_DIM; ++k) wcol[k] = We[k * DIM + lane];
    float bias = be[lane];
    __syncthreads();

    int stt = offs[b * NSLICE];
    int end = offs[b * NSLICE + NSLICE];

    // ---- edge phase: 64-record batches per wave ----
    #pragma unroll 1
    for (int i0e = stt + wv * 64; i0e < end; i0e += 512) {
        int p = i0e + lane;
        if (p >= end) p = end - 1;
        const int2* rp = (const int2*)(recs + (size_t)p * 6);
        int2 ra = rp[0], rb = rp[1], rc = rp[2];
        int cnt = end - i0e;
        cnt = cnt > 64 ? 64 : cnt;

        #pragma unroll 1
        for (int u0 = 0; u0 < cnt; u0 += 4) {
            int n4 = cnt - u0;
            int r0[4];
            float xv[4];
            #pragma unroll
            for (int q = 0; q < 4; ++q) {
                int uu = (u0 + q < cnt) ? (u0 + q) : (cnt - 1);
                r0[q] = __builtin_amdgcn_readlane(ra.x, uu);
            }
            #pragma unroll
            for (int q = 0; q < 4; ++q)
                xv[q] = __half2float(xh[(size_t)(r0[q] & 0x1FFFF) * DIM + lane]);
            #pragma unroll
            for (int q = 0; q < 4; ++q) {
                if (q < n4) {   // wave-uniform
                    int uu = u0 + q;
                    unsigned w0 = (unsigned)__builtin_amdgcn_readlane(ra.y, uu);
                    unsigned w1 = (unsigned)__builtin_amdgcn_readlane(rb.x, uu);
                    unsigned w2 = (unsigned)__builtin_amdgcn_readlane(rb.y, uu);
                    unsigned w3 = (unsigned)__builtin_amdgcn_readlane(rc.x, uu);
                    unsigned w4 = (unsigned)__builtin_amdgcn_readlane(rc.y, uu);
                    float m = bias;
                    m = fmaf(bflo(w0), wcol[0], m); m = fmaf(bfhi(w0), wcol[1], m);
                    m = fmaf(bflo(w1), wcol[2], m); m = fmaf(bfhi(w1), wcol[3], m);
                    m = fmaf(bflo(w2), wcol[4], m); m = fmaf(bfhi(w2), wcol[5], m);
                    m = fmaf(bflo(w3), wcol[6], m); m = fmaf(bfhi(w3), wcol[7], m);
                    m = fmaf(bflo(w4), wcol[8], m); m = fmaf(bfhi(w4), wcol[9], m);
                    m = fmaxf(m + xv[q], 0.0f);
                    int nl = (r0[q] >> 17) & 63;
                    atomicAdd(&sA[lane * 65 + nl], m);   // ds_add_f32, 2-way = free
                }
            }
        }
    }
    __syncthreads();

    // ---- GEMM1: T = ReLU(H @ W1 + b1), 4 nodes x 2 feats per thread ----
    int i0 = (tid & 15) * 4;
    int j0 = (tid >> 4) * 2;

    float acc1[4][2] = {};
    #pragma unroll 8
    for (int k = 0; k < DIM; ++k) {
        float a0 = sA[k * 65 + i0 + 0];
        float a1 = sA[k * 65 + i0 + 1];
        float a2 = sA[k * 65 + i0 + 2];
        float a3 = sA[k * 65 + i0 + 3];
        float bw0 = sW[k * DIM + j0];
        float bw1 = sW[k * DIM + j0 + 1];
        acc1[0][0] = fmaf(a0, bw0, acc1[0][0]); acc1[0][1] = fmaf(a0, bw1, acc1[0][1]);
        acc1[1][0] = fmaf(a1, bw0, acc1[1][0]); acc1[1][1] = fmaf(a1, bw1, acc1[1][1]);
        acc1[2][0] = fmaf(a2, bw0, acc1[2][0]); acc1[2][1] = fmaf(a2, bw1, acc1[2][1]);
        acc1[3][0] = fmaf(a3, bw0, acc1[3][0]); acc1[3][1] = fmaf(a3, bw1, acc1[3][1]);
    }
    __syncthreads();   // all GEMM1 reads done before sA/sW overwrite

    float b1a[2] = {b1[j0], b1[j0 + 1]};
    #pragma unroll
    for (int c = 0; c < 2; ++c)
        #pragma unroll
        for (int a = 0; a < 4; ++a)
            sA[(j0 + c) * 65 + i0 + a] = fmaxf(acc1[a][c] + b1a[c], 0.0f);
    for (int i = tid; i < DIM * DIM; i += 512) sW[i] = W2[i];
    __syncthreads();

    // ---- GEMM2 ----
    float acc2[4][2] = {};
    #pragma unroll 8
    for (int k = 0; k < DIM; ++k) {
        float a0 = sA[k * 65 + i0 + 0];
        float a1 = sA[k * 65 + i0 + 1];
        float a2 = sA[k * 65 + i0 + 2];
        float a3 = sA[k * 65 + i0 + 3];
        float bw0 = sW[k * DIM + j0];
        float bw1 = sW[k * DIM + j0 + 1];
        acc2[0][0] = fmaf(a0, bw0, acc2[0][0]); acc2[0][1] = fmaf(a0, bw1, acc2[0][1]);
        acc2[1][0] = fmaf(a1, bw0, acc2[1][0]); acc2[1][1] = fmaf(a1, bw1, acc2[1][1]);
        acc2[2][0] = fmaf(a2, bw0, acc2[2][0]); acc2[2][1] = fmaf(a2, bw1, acc2[2][1]);
        acc2[3][0] = fmaf(a3, bw0, acc2[3][0]); acc2[3][1] = fmaf(a3, bw1, acc2[3][1]);
    }

    float b2a[2] = {b2[j0], b2[j0 + 1]};
    float ps[2] = {0.f, 0.f};
    float pq[2] = {0.f, 0.f};
    #pragma unroll
    for (int a = 0; a < 4; ++a) {
        int n = base + i0 + a;
        float r0 = fmaxf(acc2[a][0] + b2a[0], 0.0f);
        float r1 = fmaxf(acc2[a][1] + b2a[1], 0.0f);
        if (n < N_NODES) {
            *(float2*)&out[(size_t)n * DIM + j0] = make_float2(r0, r1);
            ps[0] += r0; ps[1] += r1;
            pq[0] += r0 * r0; pq[1] += r1 * r1;
        }
    }
    #pragma unroll
    for (int m = 1; m < 16; m <<= 1) {
        #pragma unroll
        for (int c = 0; c < 2; ++c) {
            ps[c] += __shfl_xor(ps[c], m, 64);
            pq[c] += __shfl_xor(pq[c], m, 64);
        }
    }
    if ((lane & 15) == 0) {
        #pragma unroll
        for (int c = 0; c < 2; ++c) {
            unsafeAtomicAdd(&sums[j0 + c], ps[c]);
            unsafeAtomicAdd(&sums[64 + j0 + c], pq[c]);
        }
    }
}

// -----------------------------------------------------------------------------
// BN stats + apply
// -----------------------------------------------------------------------------
extern "C" __global__ void bn_stats_kernel(float* __restrict__ sums,
                                           const float* __restrict__ gamma,
                                           const float* __restrict__ beta)
{
    int f = threadIdx.x;
    float inv_n = 1.0f / (float)N_NODES;
    float mean = sums[f] * inv_n;
    float var  = sums[64 + f] * inv_n - mean * mean;
    float sc   = gamma[f] * rsqrtf(var + BN_EPS);
    sums[128 + f] = sc;
    sums[192 + f] = beta[f] - mean * sc;
}

extern "C" __global__ __launch_bounds__(256)
void bn_apply_kernel(float* __restrict__ out, const float* __restrict__ sums)
{
    int j = blockIdx.x * 256 + threadIdx.x;
    int f0 = (j & 15) * 4;
    float4 sc = *(const float4*)&sums[128 + f0];
    float4 sh = *(const float4*)&sums[192 + f0];
    float4 v = ((float4*)out)[j];
    v.x = fmaf(v.x, sc.x, sh.x);
    v.y = fmaf(v.y, sc.y, sh.y);
    v.z = fmaf(v.z, sc.z, sh.z);
    v.w = fmaf(v.w, sc.w, sh.w);
    ((float4*)out)[j] = v;
}

extern "C" void kernel_launch(void* const* d_in, const int* in_sizes, int n_in,
                              void* d_out, int out_size, void* d_ws, size_t ws_size,
                              hipStream_t stream)
{
    const float* x     = (const float*)d_in[0];
    const int*   ei    = (const int*)  d_in[1];
    const float* ea    = (const float*)d_in[2];
    const float* We    = (const float*)d_in[3];
    const float* be    = (const float*)d_in[4];
    const float* W1    = (const float*)d_in[5];
    const float* b1    = (const float*)d_in[6];
    const float* W2    = (const float*)d_in[7];
    const float* b2    = (const float*)d_in[8];
    const float* gamma = (const float*)d_in[9];
    const float* beta  = (const float*)d_in[10];

    float* out  = (float*)d_out;
    int*   wsi  = (int*)d_ws;
    int*   hist = wsi + HIST_OFF;
    float* sums = (float*)(wsi + SUMS_OFF);
    int*   cur  = wsi + CUR_OFF;
    int*   offs = wsi + OFFS_OFF;
    int*   recs = wsi + RECS_OFF;
    __half* xh  = (__half*)(wsi + XH_OFF);

    // zero hist + BN sums (adjacent) in one memset
    hipMemsetAsync(wsi, 0, (size_t)(NCOUNT + 256) * sizeof(int), stream);

    prep_kernel<<<1024, 256, 0, stream>>>(x, (__half2*)xh, ei, hist);
    scan_kernel<<<1, 1024, 0, stream>>>(hist, offs, cur);
    scatter_kernel<<<(N_EDGES + 255) / 256, 256, 0, stream>>>(ei, ea, cur, recs);

    gine_fused_kernel<<<NBINS, 512, 0, stream>>>(
        xh, x, offs, recs, We, be, W1, b1, W2, b2, out, sums);

    bn_stats_kernel<<<1, 64, 0, stream>>>(sums, gamma, beta);

    bn_apply_kernel<<<(N_NODES * DIM / 4) / 256, 256, 0, stream>>>(out, sums);
}